// Round 5
// baseline (524.841 us; speedup 1.0000x reference)
//
#include <hip/hip_runtime.h>
#include <hip/hip_bf16.h>

// AttnBlock2d: GN -> q/k/v 1x1conv -> softmax(q^T k / sqrt(C)) -> v@alpha -> proj -> +x
// B=8, C=256, H*W=4096. bf16 MFMA, fp32 accum.
// R5: attn = 2-wave/64-row blocks (512 blocks, ~2 independent blocks/CU so stalls
// overlap across blocks), full-c waves (no QK duplication), single-buffered KVBLK=32,
// V kept granule-planar in GLOBAL memory (coalesced staging; LDS layout = R4's).

typedef unsigned int u32;
typedef unsigned short u16;
typedef __bf16 bf16x8 __attribute__((ext_vector_type(8)));
typedef float f32x4 __attribute__((ext_vector_type(4)));
typedef float f32x16 __attribute__((ext_vector_type(16)));

#define GAS __attribute__((address_space(1)))
#define LAS __attribute__((address_space(3)))

__device__ __forceinline__ u16 f2bf(float f) {
  union { float f; u32 u; } v; v.f = f;
  return (u16)((v.u + 0x7fffu + ((v.u >> 16) & 1u)) >> 16);
}

__device__ __forceinline__ f32x4 mfma16(bf16x8 a, bf16x8 b, f32x4 c) {
  return __builtin_amdgcn_mfma_f32_16x16x32_bf16(a, b, c, 0, 0, 0);
}
__device__ __forceinline__ f32x16 mfma32(bf16x8 a, bf16x8 b, f32x16 c) {
  return __builtin_amdgcn_mfma_f32_32x32x16_bf16(a, b, c, 0, 0, 0);
}

// Stage [ROWS][ROWB bytes] row-major bf16 tile into LDS via global_load_lds,
// XOR swizzle on the SOURCE side (linear dest + inverse-swz source).
template<int ROWB, int MASK, int ITERS, int NT>
__device__ __forceinline__ void stage_swz(u16* lds, const u16* g, int ldg, int tid) {
#pragma unroll
  for (int it = 0; it < ITERS; ++it) {
    int idx = it * NT + tid;
    int off = idx * 16;
    int row = off / ROWB;
    int slot = off % ROWB;
    int sem = slot ^ ((row & MASK) << 4);
    const u16* src = g + (long)row * ldg + (sem >> 1);
    u16* dst = lds + (long)(idx & ~63) * 8;
    __builtin_amdgcn_global_load_lds((const GAS u32*)src, (LAS u32*)dst, 16, 0, 0);
  }
}

// Stage a fully-contiguous region (granule-planar V tile): linear -> linear.
template<int ITERS, int NT>
__device__ __forceinline__ void stage_lin(u16* lds, const u16* g, int tid) {
#pragma unroll
  for (int it = 0; it < ITERS; ++it) {
    int idx = it * NT + tid;
    const u16* src = g + (long)idx * 8;
    u16* dst = lds + (long)(idx & ~63) * 8;
    __builtin_amdgcn_global_load_lds((const GAS u32*)src, (LAS u32*)dst, 16, 0, 0);
  }
}

template<int ROWB, int MASK>
__device__ __forceinline__ bf16x8 ldfrag(const u16* lds, int row, int kbyte) {
  int off = row * ROWB + (kbyte ^ ((row & MASK) << 4));
  return *(const bf16x8*)((const char*)lds + off);
}

// ---------------- weight fp32 -> bf16 ----------------
__global__ __launch_bounds__(256) void convert_w(
    const float* __restrict__ w0, const float* __restrict__ w1,
    const float* __restrict__ w2, const float* __restrict__ w3,
    u16* __restrict__ out) {
  int i = blockIdx.x * 256 + threadIdx.x;
  int seg = i >> 16, idx = i & 65535;
  const float* w = seg == 0 ? w0 : seg == 1 ? w1 : seg == 2 ? w2 : w3;
  out[i] = f2bf(w[idx]);
}

// ---------------- GroupNorm: x [B][C][N] fp32 -> h_t [B][N][C] bf16 ----------------
__global__ __launch_bounds__(256) void gn_kernel(
    const float* __restrict__ x, const float* __restrict__ gamma,
    const float* __restrict__ beta, u16* __restrict__ ht) {
  int tid = threadIdx.x;
  int b = blockIdx.x >> 4;
  int grp = blockIdx.x & 15;
  const float* xg = x + ((long)b * 256 + grp * 16) * 4096;

  float s = 0.f, ss = 0.f;
  const float4* x4 = (const float4*)xg;
#pragma unroll 4
  for (int it = 0; it < 64; ++it) {
    float4 v = x4[it * 256 + tid];
    s += v.x + v.y + v.z + v.w;
    ss += v.x * v.x + v.y * v.y + v.z * v.z + v.w * v.w;
  }
#pragma unroll
  for (int d = 1; d < 64; d <<= 1) {
    s += __shfl_xor(s, d);
    ss += __shfl_xor(ss, d);
  }
  __shared__ float red[10];
  int lane = tid & 63, wave = tid >> 6;
  if (lane == 0) { red[wave] = s; red[4 + wave] = ss; }
  __syncthreads();
  if (tid == 0) {
    float S = red[0] + red[1] + red[2] + red[3];
    float SS = red[4] + red[5] + red[6] + red[7];
    float mean = S * (1.f / 65536.f);
    float var = SS * (1.f / 65536.f) - mean * mean;
    red[8] = mean;
    red[9] = rsqrtf(var + 1e-6f);
  }
  __syncthreads();
  float mean = red[8], rstd = red[9];

  float a[16], bb[16];
#pragma unroll
  for (int c = 0; c < 16; ++c) {
    float gm = gamma[grp * 16 + c];
    float bt = beta[grp * 16 + c];
    a[c] = gm * rstd;
    bb[c] = bt - mean * a[c];
  }
  u16* hb = ht + (long)b * 4096 * 256 + grp * 16;
  for (int it = 0; it < 16; ++it) {
    int n = it * 256 + tid;
    __align__(16) u16 tmp[16];
#pragma unroll
    for (int c = 0; c < 16; ++c)
      tmp[c] = f2bf(xg[(long)c * 4096 + n] * a[c] + bb[c]);
    u16* dst = hb + (long)n * 256;
    ((uint4*)dst)[0] = ((uint4*)tmp)[0];
    ((uint4*)dst)[1] = ((uint4*)tmp)[1];
  }
}

// ---------------- fused QKV GEMM ----------------
// q_t, k_t out [pos][o] bf16 (q pre-scaled by C^-0.5*log2e);
// v out granule-planar: vgp[b][jt=pos/32][g=(pos/8)&3][o][pos&7] bf16.
__global__ __launch_bounds__(256) void gemm_qkv(
    const u16* __restrict__ ht, const u16* __restrict__ wbf,
    u16* __restrict__ qtb, u16* __restrict__ ktb, u16* __restrict__ vcb,
    const float* __restrict__ bq, const float* __restrict__ bk,
    const float* __restrict__ bv) {
  __shared__ __align__(16) u16 as[64 * 64];
  __shared__ __align__(16) u16 bqs[64 * 64];
  __shared__ __align__(16) u16 bks[64 * 64];
  __shared__ __align__(16) u16 bvs[64 * 64];
  int tid = threadIdx.x;
  int lane = tid & 63, wave = tid >> 6;
  int g = lane >> 4, lr = lane & 15;
  int wm = wave >> 1, wn = wave & 1;
  const u16* Ab = ht + (long)blockIdx.x * 64 * 256;
  const u16* Wq = wbf + (long)blockIdx.y * 64 * 256;

  f32x4 zero = {0.f, 0.f, 0.f, 0.f};
  f32x4 acc[3][2][2];
#pragma unroll
  for (int w = 0; w < 3; ++w)
#pragma unroll
    for (int i = 0; i < 2; ++i)
#pragma unroll
      for (int j = 0; j < 2; ++j) acc[w][i][j] = zero;

  for (int k0 = 0; k0 < 256; k0 += 64) {
    stage_swz<128, 7, 2, 256>(as, Ab + k0, 256, tid);
    stage_swz<128, 7, 2, 256>(bqs, Wq + k0, 256, tid);
    stage_swz<128, 7, 2, 256>(bks, Wq + 65536 + k0, 256, tid);
    stage_swz<128, 7, 2, 256>(bvs, Wq + 131072 + k0, 256, tid);
    __syncthreads();
#pragma unroll
    for (int ks = 0; ks < 2; ++ks) {
      int kb = ks * 64 + g * 16;
      bf16x8 a0 = ldfrag<128, 7>(as, wm * 32 + lr, kb);
      bf16x8 a1 = ldfrag<128, 7>(as, wm * 32 + 16 + lr, kb);
      __builtin_amdgcn_s_setprio(1);
      {
        bf16x8 b0 = ldfrag<128, 7>(bqs, wn * 32 + lr, kb);
        bf16x8 b1 = ldfrag<128, 7>(bqs, wn * 32 + 16 + lr, kb);
        acc[0][0][0] = mfma16(a0, b0, acc[0][0][0]);
        acc[0][0][1] = mfma16(a0, b1, acc[0][0][1]);
        acc[0][1][0] = mfma16(a1, b0, acc[0][1][0]);
        acc[0][1][1] = mfma16(a1, b1, acc[0][1][1]);
      }
      {
        bf16x8 b0 = ldfrag<128, 7>(bks, wn * 32 + lr, kb);
        bf16x8 b1 = ldfrag<128, 7>(bks, wn * 32 + 16 + lr, kb);
        acc[1][0][0] = mfma16(a0, b0, acc[1][0][0]);
        acc[1][0][1] = mfma16(a0, b1, acc[1][0][1]);
        acc[1][1][0] = mfma16(a1, b0, acc[1][1][0]);
        acc[1][1][1] = mfma16(a1, b1, acc[1][1][1]);
      }
      {
        bf16x8 b0 = ldfrag<128, 7>(bvs, wn * 32 + lr, kb);
        bf16x8 b1 = ldfrag<128, 7>(bvs, wn * 32 + 16 + lr, kb);
        acc[2][0][0] = mfma16(a0, b0, acc[2][0][0]);
        acc[2][0][1] = mfma16(a0, b1, acc[2][0][1]);
        acc[2][1][0] = mfma16(a1, b0, acc[2][1][0]);
        acc[2][1][1] = mfma16(a1, b1, acc[2][1][1]);
      }
      __builtin_amdgcn_s_setprio(0);
    }
    __syncthreads();
  }

  const float QSC = 0.0625f * 1.44269504f;   // C^-0.5 * log2(e), folded into q
  int mb = blockIdx.x * 64 + wm * 32;
  int nb = blockIdx.y * 64 + wn * 32;
  int b_ = mb >> 12;
  int posb = mb & 4095;
#pragma unroll
  for (int mi = 0; mi < 2; ++mi)
#pragma unroll
    for (int ni = 0; ni < 2; ++ni) {
      int n = nb + ni * 16 + lr;
      __align__(8) u16 v4[4];
#pragma unroll
      for (int e = 0; e < 4; ++e) {
        int m = mb + mi * 16 + 4 * g + e;
        long addr = (long)m * 256 + n;
        qtb[addr] = f2bf((acc[0][mi][ni][e] + bq[n]) * QSC);
        ktb[addr] = f2bf(acc[1][mi][ni][e] + bk[n]);
        v4[e] = f2bf(acc[2][mi][ni][e] + bv[n]);
      }
      int pos0 = posb + mi * 16 + 4 * g;          // multiple of 4
      int jt = pos0 >> 5, gg = (pos0 >> 3) & 3, js = pos0 & 7;
      *(uint2*)(vcb + (long)b_ * 1048576 + (long)jt * 8192 + gg * 2048 + n * 8 + js)
          = *(uint2*)v4;
    }
}

// ---------------- proj GEMM + residual: D[m=o][n=pos] fp32 ----------------
__global__ __launch_bounds__(256) void gemm_proj(
    const u16* __restrict__ A, const u16* __restrict__ Bt,
    float* __restrict__ outp, const float* __restrict__ bias,
    const float* __restrict__ resid) {
  __shared__ __align__(16) u16 as[64 * 64];
  __shared__ __align__(16) u16 bs[64 * 64];
  int tid = threadIdx.x;
  int lane = tid & 63, wave = tid >> 6;
  int g = lane >> 4, lr = lane & 15;
  int wm = wave >> 1, wn = wave & 1;
  int z = blockIdx.z;
  const u16* Ab = A + (long)blockIdx.x * 64 * 256;
  const u16* Bb = Bt + (long)z * 4096 * 256 + (long)blockIdx.y * 64 * 256;

  f32x4 zero = {0.f, 0.f, 0.f, 0.f};
  f32x4 acc[2][2];
#pragma unroll
  for (int i = 0; i < 2; ++i)
#pragma unroll
    for (int j = 0; j < 2; ++j) acc[i][j] = zero;

  for (int k0 = 0; k0 < 256; k0 += 64) {
    stage_swz<128, 7, 2, 256>(as, Ab + k0, 256, tid);
    stage_swz<128, 7, 2, 256>(bs, Bb + k0, 256, tid);
    __syncthreads();
#pragma unroll
    for (int ks = 0; ks < 2; ++ks) {
      int kb = ks * 64 + g * 16;
      bf16x8 a0 = ldfrag<128, 7>(as, wm * 32 + lr, kb);
      bf16x8 a1 = ldfrag<128, 7>(as, wm * 32 + 16 + lr, kb);
      bf16x8 b0 = ldfrag<128, 7>(bs, wn * 32 + lr, kb);
      bf16x8 b1 = ldfrag<128, 7>(bs, wn * 32 + 16 + lr, kb);
      acc[0][0] = mfma16(a0, b0, acc[0][0]);
      acc[0][1] = mfma16(a0, b1, acc[0][1]);
      acc[1][0] = mfma16(a1, b0, acc[1][0]);
      acc[1][1] = mfma16(a1, b1, acc[1][1]);
    }
    __syncthreads();
  }

  int mb = blockIdx.x * 64 + wm * 32;
  int nb = blockIdx.y * 64 + wn * 32;
#pragma unroll
  for (int mi = 0; mi < 2; ++mi)
#pragma unroll
    for (int ni = 0; ni < 2; ++ni)
#pragma unroll
      for (int e = 0; e < 4; ++e) {
        int m = mb + mi * 16 + 4 * g + e;
        int n = nb + ni * 16 + lr;
        long addr = (long)z * 1048576 + (long)m * 4096 + n;
        outp[addr] = acc[mi][ni][e] + bias[m] + resid[addr];
      }
}

// ---------------- flash attention: 2-wave blocks, full-c waves ----------------
// 512 blocks (b = bid&7 XCD-aligned), 128 thr = 2 waves, 32 q-rows each (lane owns
// one q-row via swapped QK^T). KVBLK=32 single-buffered (33KB LDS -> up to 4
// blocks/CU; VGPR ~245 -> 8 waves/CU => ~2 independent blocks co-resident whose
// compute hides each other's stage/barrier stalls). P in regs via lane^32 exchange.
__global__ __launch_bounds__(128, 2) void attn_flash(
    const u16* __restrict__ qt, const u16* __restrict__ kt,
    const u16* __restrict__ vgp, u16* __restrict__ ot) {
  __shared__ __align__(16) u16 ksT[32 * 256];     // K tile [j=32][c=256], swizzled rows
  __shared__ __align__(16) u16 vsT[4 * 256 * 8];  // V tile granule-planar [g][c][8]
  __shared__ float fws[64];                       // [wave][32] broadcast scratch

  int tid = threadIdx.x;
  int lane = tid & 63;
  int h = lane >> 5, lr = lane & 31;
  int w = tid >> 6;
  int bid = blockIdx.x;
  long b = bid & 7;
  int i0 = (bid >> 3) * 64;

  const u16* kb = kt + b * 4096 * 256;
  const u16* vb = vgp + b * 1048576;
  float* fw = fws + w * 32;

  // Q: lane owns q-row (i0 + w*32 + lr); frag kk holds c = kk*16 + 8h + e
  const u16* qrow = qt + ((b * 4096 + i0 + w * 32 + lr) << 8) + h * 8;
  bf16x8 qreg[16];
#pragma unroll
  for (int kk = 0; kk < 16; ++kk)
    qreg[kk] = *(const bf16x8*)(qrow + kk * 16);

  f32x16 zero16 = {0,0,0,0,0,0,0,0,0,0,0,0,0,0,0,0};
  f32x16 acc[8];                 // O[row pattern][c = ct*32 + lr]
#pragma unroll
  for (int ct = 0; ct < 8; ++ct) acc[ct] = zero16;
  float mrun = -3e38f, lsum = 0.f;

  for (int t = 0; t < 128; ++t) {
    __syncthreads();                                   // prev compute done
    stage_swz<512, 7, 8, 128>(ksT, kb + (long)t * 32 * 256, 256, tid);
    stage_lin<8, 128>(vsT, vb + (long)t * 8192, tid);
    __syncthreads();                                   // stage complete

    // S^T = K * Q (log2 units): D col = lane&31 = own q-row, D row = j
    f32x16 sacc = zero16;
    __builtin_amdgcn_s_setprio(1);
#pragma unroll
    for (int kk = 0; kk < 16; ++kk) {
      bf16x8 kf = ldfrag<512, 7>(ksT, lr, kk * 32 + 16 * h);
      sacc = mfma32(kf, qreg[kk], sacc);
    }
    __builtin_amdgcn_s_setprio(0);

    // row max: 16 regs + xor-32 (partner lane holds the other 16 j's)
    float mloc = sacc[0];
#pragma unroll
    for (int r = 1; r < 16; ++r) mloc = fmaxf(mloc, sacc[r]);
    mloc = fmaxf(mloc, __shfl_xor(mloc, 32));

    // defer-max: rescale only when max grew by > 8 (log2 units)
    if (!__all(mloc - mrun <= 8.f)) {
      float mnew = fmaxf(mrun, mloc);
      float al = exp2f(mrun - mnew);
      mrun = mnew;
      lsum *= al;
      if (h == 0) fw[lr] = al;
      asm volatile("s_waitcnt lgkmcnt(0)" ::: "memory");
      f32x4 fq0 = *(const f32x4*)&fw[4 * h];
      f32x4 fq1 = *(const f32x4*)&fw[8 + 4 * h];
      f32x4 fq2 = *(const f32x4*)&fw[16 + 4 * h];
      f32x4 fq3 = *(const f32x4*)&fw[24 + 4 * h];
      f32x16 alv;
#pragma unroll
      for (int e = 0; e < 4; ++e) {
        alv[e] = fq0[e]; alv[4 + e] = fq1[e]; alv[8 + e] = fq2[e]; alv[12 + e] = fq3[e];
      }
#pragma unroll
      for (int ct = 0; ct < 8; ++ct) acc[ct] *= alv;
    }

    // P = exp2(S - m), pack bf16 pairs; per-lane partial lsum
    u32 u[8];
#pragma unroll
    for (int m = 0; m < 8; ++m) {
      float p0 = exp2f(sacc[2 * m] - mrun);
      float p1 = exp2f(sacc[2 * m + 1] - mrun);
      lsum += p0 + p1;
      u[m] = (u32)f2bf(p0) | ((u32)f2bf(p1) << 16);
    }
    // half-exchange with lane^32 to assemble PV A-fragments
    u32 rv[4];
#pragma unroll
    for (int kt2 = 0; kt2 < 2; ++kt2)
#pragma unroll
      for (int idx = 0; idx < 2; ++idx) {
        u32 send = h ? u[4 * kt2 + idx] : u[4 * kt2 + 2 + idx];
        rv[kt2 * 2 + idx] = (u32)__shfl_xor((int)send, 32);
      }
    union { u32 wd[4]; bf16x8 v; } pf[2];
#pragma unroll
    for (int kt2 = 0; kt2 < 2; ++kt2) {
      pf[kt2].wd[0] = h ? rv[kt2 * 2] : u[4 * kt2];
      pf[kt2].wd[1] = h ? rv[kt2 * 2 + 1] : u[4 * kt2 + 1];
      pf[kt2].wd[2] = h ? u[4 * kt2 + 2] : rv[kt2 * 2];
      pf[kt2].wd[3] = h ? u[4 * kt2 + 3] : rv[kt2 * 2 + 1];
    }

    // PV: O[i][c] += P[i][j] * V[c][j]; V planes g: kf0 -> g=h, kf1 -> g=2+h
    __builtin_amdgcn_s_setprio(1);
#pragma unroll
    for (int ct = 0; ct < 8; ++ct) {
      int c = ct * 32 + lr;
      bf16x8 vf0 = *(const bf16x8*)(vsT + ((long)h * 256 + c) * 8);
      bf16x8 vf1 = *(const bf16x8*)(vsT + ((long)(2 + h) * 256 + c) * 8);
      acc[ct] = mfma32(pf[0].v, vf0, acc[ct]);
      acc[ct] = mfma32(pf[1].v, vf1, acc[ct]);
    }
    __builtin_amdgcn_s_setprio(0);
  }

  // epilogue: total lsum per row, broadcast 1/lsum, scale, store
  lsum += __shfl_xor(lsum, 32);
  if (h == 0) fw[lr] = 1.0f / lsum;
  asm volatile("s_waitcnt lgkmcnt(0)" ::: "memory");
  f32x4 fq0 = *(const f32x4*)&fw[4 * h];
  f32x4 fq1 = *(const f32x4*)&fw[8 + 4 * h];
  f32x4 fq2 = *(const f32x4*)&fw[16 + 4 * h];
  f32x4 fq3 = *(const f32x4*)&fw[24 + 4 * h];
  f32x16 rlv;
#pragma unroll
  for (int e = 0; e < 4; ++e) {
    rlv[e] = fq0[e]; rlv[4 + e] = fq1[e]; rlv[8 + e] = fq2[e]; rlv[12 + e] = fq3[e];
  }
  u16* ob = ot + ((b * 4096 + i0 + w * 32) << 8);
#pragma unroll
  for (int ct = 0; ct < 8; ++ct) {
    int c = ct * 32 + lr;
#pragma unroll
    for (int q = 0; q < 4; ++q)
#pragma unroll
      for (int e = 0; e < 4; ++e) {
        int i = 8 * q + 4 * h + e;
        ob[(long)i * 256 + c] = f2bf(acc[ct][4 * q + e] * rlv[4 * q + e]);
      }
  }
}

// ---------------- launcher ----------------
extern "C" void kernel_launch(void* const* d_in, const int* in_sizes, int n_in,
                              void* d_out, int out_size, void* d_ws, size_t ws_size,
                              hipStream_t stream) {
  const float* x     = (const float*)d_in[0];
  const float* gamma = (const float*)d_in[1];
  const float* beta  = (const float*)d_in[2];
  const float* wq = (const float*)d_in[3];
  const float* bq = (const float*)d_in[4];
  const float* wk = (const float*)d_in[5];
  const float* bk = (const float*)d_in[6];
  const float* wv = (const float*)d_in[7];
  const float* bv = (const float*)d_in[8];
  const float* wp = (const float*)d_in[9];
  const float* bp = (const float*)d_in[10];

  char* ws = (char*)d_ws;
  const long SZ = 16777216;            // one [B][N][C] bf16 tensor
  u16* ht  = (u16*)(ws);
  u16* qtb = (u16*)(ws + SZ);
  u16* ktb = (u16*)(ws + 2 * SZ);
  u16* vcb = (u16*)(ws + 3 * SZ);      // granule-planar V
  u16* wbf = (u16*)(ws + 4 * SZ);      // wq|wk|wv|wp, 65536 u16 each
  u16* otb = ht;                       // h dead after QKV; reuse for attn output

  convert_w<<<1024, 256, 0, stream>>>(wq, wk, wv, wp, wbf);
  gn_kernel<<<128, 256, 0, stream>>>(x, gamma, beta, ht);

  dim3 gq(512, 4, 1);   // M=B*N=32768 rows, Nn=256
  gemm_qkv<<<gq, 256, 0, stream>>>(ht, wbf, qtb, ktb, vcb, bq, bk, bv);

  attn_flash<<<512, 128, 0, stream>>>(qtb, ktb, vcb, otb);

  dim3 gp(4, 64, 8);
  gemm_proj<<<gp, 256, 0, stream>>>(wbf + 3 * 65536, otb, (float*)d_out, bp, x);
}

// Round 6
// 424.721 us; speedup vs baseline: 1.2357x; 1.2357x over previous
//
#include <hip/hip_runtime.h>
#include <hip/hip_bf16.h>

// AttnBlock2d: GN -> q/k/v 1x1conv -> softmax(q^T k / sqrt(C)) -> v@alpha -> proj -> +x
// B=8, C=256, H*W=4096. bf16 MFMA, fp32 accum.
// R6: attn = 512 blocks x 4 waves (2 rowgroups x 2 c-halves) -> 2048 waves = 2/SIMD,
// 2 independent blocks/CU. QK^T duplicated across c-twins (latency-bound, MFMA cheap).
// K now granule-planar in global (like V): all LDS frag reads linear+conflict-free,
// all staging contiguous stage_lin. KVBLK=64 staged, computed as 2x32-j subtiles.

typedef unsigned int u32;
typedef unsigned short u16;
typedef __bf16 bf16x8 __attribute__((ext_vector_type(8)));
typedef float f32x4 __attribute__((ext_vector_type(4)));
typedef float f32x16 __attribute__((ext_vector_type(16)));

#define GAS __attribute__((address_space(1)))
#define LAS __attribute__((address_space(3)))

__device__ __forceinline__ u16 f2bf(float f) {
  union { float f; u32 u; } v; v.f = f;
  return (u16)((v.u + 0x7fffu + ((v.u >> 16) & 1u)) >> 16);
}

__device__ __forceinline__ f32x4 mfma16(bf16x8 a, bf16x8 b, f32x4 c) {
  return __builtin_amdgcn_mfma_f32_16x16x32_bf16(a, b, c, 0, 0, 0);
}
__device__ __forceinline__ f32x16 mfma32(bf16x8 a, bf16x8 b, f32x16 c) {
  return __builtin_amdgcn_mfma_f32_32x32x16_bf16(a, b, c, 0, 0, 0);
}

// Stage [ROWS][ROWB bytes] row-major bf16 tile into LDS via global_load_lds,
// XOR swizzle on the SOURCE side (linear dest + inverse-swz source). (GEMMs only.)
template<int ROWB, int MASK, int ITERS, int NT>
__device__ __forceinline__ void stage_swz(u16* lds, const u16* g, int ldg, int tid) {
#pragma unroll
  for (int it = 0; it < ITERS; ++it) {
    int idx = it * NT + tid;
    int off = idx * 16;
    int row = off / ROWB;
    int slot = off % ROWB;
    int sem = slot ^ ((row & MASK) << 4);
    const u16* src = g + (long)row * ldg + (sem >> 1);
    u16* dst = lds + (long)(idx & ~63) * 8;
    __builtin_amdgcn_global_load_lds((const GAS u32*)src, (LAS u32*)dst, 16, 0, 0);
  }
}

// Stage a fully-contiguous region: linear global -> linear LDS, coalesced.
template<int ITERS, int NT>
__device__ __forceinline__ void stage_lin(u16* lds, const u16* g, int tid) {
#pragma unroll
  for (int it = 0; it < ITERS; ++it) {
    int idx = it * NT + tid;
    const u16* src = g + (long)idx * 8;
    u16* dst = lds + (long)(idx & ~63) * 8;
    __builtin_amdgcn_global_load_lds((const GAS u32*)src, (LAS u32*)dst, 16, 0, 0);
  }
}

template<int ROWB, int MASK>
__device__ __forceinline__ bf16x8 ldfrag(const u16* lds, int row, int kbyte) {
  int off = row * ROWB + (kbyte ^ ((row & MASK) << 4));
  return *(const bf16x8*)((const char*)lds + off);
}

// ---------------- weight fp32 -> bf16 ----------------
__global__ __launch_bounds__(256) void convert_w(
    const float* __restrict__ w0, const float* __restrict__ w1,
    const float* __restrict__ w2, const float* __restrict__ w3,
    u16* __restrict__ out) {
  int i = blockIdx.x * 256 + threadIdx.x;
  int seg = i >> 16, idx = i & 65535;
  const float* w = seg == 0 ? w0 : seg == 1 ? w1 : seg == 2 ? w2 : w3;
  out[i] = f2bf(w[idx]);
}

// ---------------- GroupNorm: x [B][C][N] fp32 -> h_t [B][N][C] bf16 ----------------
__global__ __launch_bounds__(256) void gn_kernel(
    const float* __restrict__ x, const float* __restrict__ gamma,
    const float* __restrict__ beta, u16* __restrict__ ht) {
  int tid = threadIdx.x;
  int b = blockIdx.x >> 4;
  int grp = blockIdx.x & 15;
  const float* xg = x + ((long)b * 256 + grp * 16) * 4096;

  float s = 0.f, ss = 0.f;
  const float4* x4 = (const float4*)xg;
#pragma unroll 4
  for (int it = 0; it < 64; ++it) {
    float4 v = x4[it * 256 + tid];
    s += v.x + v.y + v.z + v.w;
    ss += v.x * v.x + v.y * v.y + v.z * v.z + v.w * v.w;
  }
#pragma unroll
  for (int d = 1; d < 64; d <<= 1) {
    s += __shfl_xor(s, d);
    ss += __shfl_xor(ss, d);
  }
  __shared__ float red[10];
  int lane = tid & 63, wave = tid >> 6;
  if (lane == 0) { red[wave] = s; red[4 + wave] = ss; }
  __syncthreads();
  if (tid == 0) {
    float S = red[0] + red[1] + red[2] + red[3];
    float SS = red[4] + red[5] + red[6] + red[7];
    float mean = S * (1.f / 65536.f);
    float var = SS * (1.f / 65536.f) - mean * mean;
    red[8] = mean;
    red[9] = rsqrtf(var + 1e-6f);
  }
  __syncthreads();
  float mean = red[8], rstd = red[9];

  float a[16], bb[16];
#pragma unroll
  for (int c = 0; c < 16; ++c) {
    float gm = gamma[grp * 16 + c];
    float bt = beta[grp * 16 + c];
    a[c] = gm * rstd;
    bb[c] = bt - mean * a[c];
  }
  u16* hb = ht + (long)b * 4096 * 256 + grp * 16;
  for (int it = 0; it < 16; ++it) {
    int n = it * 256 + tid;
    __align__(16) u16 tmp[16];
#pragma unroll
    for (int c = 0; c < 16; ++c)
      tmp[c] = f2bf(xg[(long)c * 4096 + n] * a[c] + bb[c]);
    u16* dst = hb + (long)n * 256;
    ((uint4*)dst)[0] = ((uint4*)tmp)[0];
    ((uint4*)dst)[1] = ((uint4*)tmp)[1];
  }
}

// ---------------- fused QKV GEMM ----------------
// q_t out [pos][o] bf16 (pre-scaled by C^-0.5*log2e).
// k out granule-planar: kgp[b][jt=pos/32][cg=o/8][j=pos&31][o&7].
// v out granule-planar: vgp[b][jt=pos/32][g=(pos/8)&3][o][pos&7].
__global__ __launch_bounds__(256) void gemm_qkv(
    const u16* __restrict__ ht, const u16* __restrict__ wbf,
    u16* __restrict__ qtb, u16* __restrict__ ktb, u16* __restrict__ vcb,
    const float* __restrict__ bq, const float* __restrict__ bk,
    const float* __restrict__ bv) {
  __shared__ __align__(16) u16 as[64 * 64];
  __shared__ __align__(16) u16 bqs[64 * 64];
  __shared__ __align__(16) u16 bks[64 * 64];
  __shared__ __align__(16) u16 bvs[64 * 64];
  int tid = threadIdx.x;
  int lane = tid & 63, wave = tid >> 6;
  int g = lane >> 4, lr = lane & 15;
  int wm = wave >> 1, wn = wave & 1;
  const u16* Ab = ht + (long)blockIdx.x * 64 * 256;
  const u16* Wq = wbf + (long)blockIdx.y * 64 * 256;

  f32x4 zero = {0.f, 0.f, 0.f, 0.f};
  f32x4 acc[3][2][2];
#pragma unroll
  for (int w = 0; w < 3; ++w)
#pragma unroll
    for (int i = 0; i < 2; ++i)
#pragma unroll
      for (int j = 0; j < 2; ++j) acc[w][i][j] = zero;

  for (int k0 = 0; k0 < 256; k0 += 64) {
    stage_swz<128, 7, 2, 256>(as, Ab + k0, 256, tid);
    stage_swz<128, 7, 2, 256>(bqs, Wq + k0, 256, tid);
    stage_swz<128, 7, 2, 256>(bks, Wq + 65536 + k0, 256, tid);
    stage_swz<128, 7, 2, 256>(bvs, Wq + 131072 + k0, 256, tid);
    __syncthreads();
#pragma unroll
    for (int ks = 0; ks < 2; ++ks) {
      int kb = ks * 64 + g * 16;
      bf16x8 a0 = ldfrag<128, 7>(as, wm * 32 + lr, kb);
      bf16x8 a1 = ldfrag<128, 7>(as, wm * 32 + 16 + lr, kb);
      __builtin_amdgcn_s_setprio(1);
      {
        bf16x8 b0 = ldfrag<128, 7>(bqs, wn * 32 + lr, kb);
        bf16x8 b1 = ldfrag<128, 7>(bqs, wn * 32 + 16 + lr, kb);
        acc[0][0][0] = mfma16(a0, b0, acc[0][0][0]);
        acc[0][0][1] = mfma16(a0, b1, acc[0][0][1]);
        acc[0][1][0] = mfma16(a1, b0, acc[0][1][0]);
        acc[0][1][1] = mfma16(a1, b1, acc[0][1][1]);
      }
      {
        bf16x8 b0 = ldfrag<128, 7>(bks, wn * 32 + lr, kb);
        bf16x8 b1 = ldfrag<128, 7>(bks, wn * 32 + 16 + lr, kb);
        acc[1][0][0] = mfma16(a0, b0, acc[1][0][0]);
        acc[1][0][1] = mfma16(a0, b1, acc[1][0][1]);
        acc[1][1][0] = mfma16(a1, b0, acc[1][1][0]);
        acc[1][1][1] = mfma16(a1, b1, acc[1][1][1]);
      }
      {
        bf16x8 b0 = ldfrag<128, 7>(bvs, wn * 32 + lr, kb);
        bf16x8 b1 = ldfrag<128, 7>(bvs, wn * 32 + 16 + lr, kb);
        acc[2][0][0] = mfma16(a0, b0, acc[2][0][0]);
        acc[2][0][1] = mfma16(a0, b1, acc[2][0][1]);
        acc[2][1][0] = mfma16(a1, b0, acc[2][1][0]);
        acc[2][1][1] = mfma16(a1, b1, acc[2][1][1]);
      }
      __builtin_amdgcn_s_setprio(0);
    }
    __syncthreads();
  }

  const float QSC = 0.0625f * 1.44269504f;   // C^-0.5 * log2(e), folded into q
  int mb = blockIdx.x * 64 + wm * 32;
  int nb = blockIdx.y * 64 + wn * 32;
  int b_ = mb >> 12;
  int posb = mb & 4095;
#pragma unroll
  for (int mi = 0; mi < 2; ++mi)
#pragma unroll
    for (int ni = 0; ni < 2; ++ni) {
      int n = nb + ni * 16 + lr;
      int pos0 = posb + mi * 16 + 4 * g;          // rows pos0..pos0+3 (same 32-tile)
      int jt = pos0 >> 5, jj = pos0 & 31;
      long kbase = (long)b_ * 1048576 + (long)jt * 8192 + (n >> 3) * 256 + jj * 8 + (n & 7);
      __align__(8) u16 v4[4];
#pragma unroll
      for (int e = 0; e < 4; ++e) {
        int m = mb + mi * 16 + 4 * g + e;
        long addr = (long)m * 256 + n;
        qtb[addr] = f2bf((acc[0][mi][ni][e] + bq[n]) * QSC);
        ktb[kbase + e * 8] = f2bf(acc[1][mi][ni][e] + bk[n]);
        v4[e] = f2bf(acc[2][mi][ni][e] + bv[n]);
      }
      int gg = (pos0 >> 3) & 3, js = pos0 & 7;
      *(uint2*)(vcb + (long)b_ * 1048576 + (long)jt * 8192 + gg * 2048 + n * 8 + js)
          = *(uint2*)v4;
    }
}

// ---------------- proj GEMM + residual: D[m=o][n=pos] fp32 ----------------
__global__ __launch_bounds__(256) void gemm_proj(
    const u16* __restrict__ A, const u16* __restrict__ Bt,
    float* __restrict__ outp, const float* __restrict__ bias,
    const float* __restrict__ resid) {
  __shared__ __align__(16) u16 as[64 * 64];
  __shared__ __align__(16) u16 bs[64 * 64];
  int tid = threadIdx.x;
  int lane = tid & 63, wave = tid >> 6;
  int g = lane >> 4, lr = lane & 15;
  int wm = wave >> 1, wn = wave & 1;
  int z = blockIdx.z;
  const u16* Ab = A + (long)blockIdx.x * 64 * 256;
  const u16* Bb = Bt + (long)z * 4096 * 256 + (long)blockIdx.y * 64 * 256;

  f32x4 zero = {0.f, 0.f, 0.f, 0.f};
  f32x4 acc[2][2];
#pragma unroll
  for (int i = 0; i < 2; ++i)
#pragma unroll
    for (int j = 0; j < 2; ++j) acc[i][j] = zero;

  for (int k0 = 0; k0 < 256; k0 += 64) {
    stage_swz<128, 7, 2, 256>(as, Ab + k0, 256, tid);
    stage_swz<128, 7, 2, 256>(bs, Bb + k0, 256, tid);
    __syncthreads();
#pragma unroll
    for (int ks = 0; ks < 2; ++ks) {
      int kb = ks * 64 + g * 16;
      bf16x8 a0 = ldfrag<128, 7>(as, wm * 32 + lr, kb);
      bf16x8 a1 = ldfrag<128, 7>(as, wm * 32 + 16 + lr, kb);
      bf16x8 b0 = ldfrag<128, 7>(bs, wn * 32 + lr, kb);
      bf16x8 b1 = ldfrag<128, 7>(bs, wn * 32 + 16 + lr, kb);
      acc[0][0] = mfma16(a0, b0, acc[0][0]);
      acc[0][1] = mfma16(a0, b1, acc[0][1]);
      acc[1][0] = mfma16(a1, b0, acc[1][0]);
      acc[1][1] = mfma16(a1, b1, acc[1][1]);
    }
    __syncthreads();
  }

  int mb = blockIdx.x * 64 + wm * 32;
  int nb = blockIdx.y * 64 + wn * 32;
#pragma unroll
  for (int mi = 0; mi < 2; ++mi)
#pragma unroll
    for (int ni = 0; ni < 2; ++ni)
#pragma unroll
      for (int e = 0; e < 4; ++e) {
        int m = mb + mi * 16 + 4 * g + e;
        int n = nb + ni * 16 + lr;
        long addr = (long)z * 1048576 + (long)m * 4096 + n;
        outp[addr] = acc[mi][ni][e] + bias[m] + resid[addr];
      }
}

// ---------------- flash attention: 4-wave blocks, c-split twins ----------------
// 512 blocks (b = bid&7 XCD-aligned), 256 thr = 4 waves: rg = wave>>1 (32-row group),
// chalf = wave&1 (O c-half, QK^T duplicated across twins). Lane owns ONE q-row
// (swapped QK^T). KVBLK=64 staged contiguously (K,V both granule-planar in global ->
// linear conflict-free LDS reads), computed as two 32-j subtiles. 2048 waves = 2/SIMD,
// 2 independent blocks/CU cover each other's stage/barrier stalls.
__global__ __launch_bounds__(256, 2) void attn_flash(
    const u16* __restrict__ qt, const u16* __restrict__ kgp,
    const u16* __restrict__ vgp, u16* __restrict__ ot) {
  __shared__ __align__(16) u16 ksT[16384];   // 2 subtiles x [cg 32][j 32][8] = 32KB
  __shared__ __align__(16) u16 vsT[16384];   // 2 subtiles x [g 4][c 256][8] = 32KB
  __shared__ float fws[128];                 // [wave][32] broadcast scratch

  int tid = threadIdx.x;
  int lane = tid & 63;
  int h = lane >> 5, lr = lane & 31;
  int wave = tid >> 6;
  int rg = wave >> 1, chalf = wave & 1;
  int bid = blockIdx.x;
  long b = bid & 7;
  int i0 = (bid >> 3) * 64;

  const u16* kb = kgp + b * 1048576;
  const u16* vb = vgp + b * 1048576;
  float* fw = fws + wave * 32;

  // Q: lane owns q-row (i0 + rg*32 + lr); frag kk holds c = kk*16 + 8h + e
  const u16* qrow = qt + ((b * 4096 + i0 + rg * 32 + lr) << 8) + h * 8;
  bf16x8 qreg[16];
#pragma unroll
  for (int kk = 0; kk < 16; ++kk)
    qreg[kk] = *(const bf16x8*)(qrow + kk * 16);

  f32x16 zero16 = {0,0,0,0,0,0,0,0,0,0,0,0,0,0,0,0};
  f32x16 acc[4];                 // O[row pattern][c = chalf*128 + ct*32 + lr]
#pragma unroll
  for (int ct = 0; ct < 4; ++ct) acc[ct] = zero16;
  float mrun = -3e38f, lsum = 0.f;

  for (int t = 0; t < 64; ++t) {
    __syncthreads();                                   // prev compute done
    stage_lin<8, 256>(ksT, kb + (long)t * 16384, tid);
    stage_lin<8, 256>(vsT, vb + (long)t * 16384, tid);
    __syncthreads();                                   // stage complete

#pragma unroll
    for (int s = 0; s < 2; ++s) {
      const u16* ksl = ksT + s * 8192;
      const u16* vsl = vsT + s * 8192;

      // S^T = K * Q (log2 units): D col = lane&31 = own q-row, D row = j
      f32x16 sacc = zero16;
      __builtin_amdgcn_s_setprio(1);
#pragma unroll
      for (int kk = 0; kk < 16; ++kk) {
        bf16x8 kf = *(const bf16x8*)(ksl + ((2 * kk + h) * 32 + lr) * 8);
        sacc = mfma32(kf, qreg[kk], sacc);
      }
      __builtin_amdgcn_s_setprio(0);

      // row max: 16 regs + xor-32 (partner lane holds the other 16 j's)
      float mloc = sacc[0];
#pragma unroll
      for (int r = 1; r < 16; ++r) mloc = fmaxf(mloc, sacc[r]);
      mloc = fmaxf(mloc, __shfl_xor(mloc, 32));

      // defer-max: rescale only when max grew by > 8 (log2 units)
      if (!__all(mloc - mrun <= 8.f)) {
        float mnew = fmaxf(mrun, mloc);
        float al = exp2f(mrun - mnew);
        mrun = mnew;
        lsum *= al;
        if (h == 0) fw[lr] = al;
        asm volatile("s_waitcnt lgkmcnt(0)" ::: "memory");
        f32x4 fq0 = *(const f32x4*)&fw[4 * h];
        f32x4 fq1 = *(const f32x4*)&fw[8 + 4 * h];
        f32x4 fq2 = *(const f32x4*)&fw[16 + 4 * h];
        f32x4 fq3 = *(const f32x4*)&fw[24 + 4 * h];
        f32x16 alv;
#pragma unroll
        for (int e = 0; e < 4; ++e) {
          alv[e] = fq0[e]; alv[4 + e] = fq1[e]; alv[8 + e] = fq2[e]; alv[12 + e] = fq3[e];
        }
#pragma unroll
        for (int ct = 0; ct < 4; ++ct) acc[ct] *= alv;
      }

      // P = exp2(S - m), pack bf16 pairs; per-lane partial lsum
      u32 u[8];
#pragma unroll
      for (int m = 0; m < 8; ++m) {
        float p0 = exp2f(sacc[2 * m] - mrun);
        float p1 = exp2f(sacc[2 * m + 1] - mrun);
        lsum += p0 + p1;
        u[m] = (u32)f2bf(p0) | ((u32)f2bf(p1) << 16);
      }
      // half-exchange with lane^32 to assemble PV A-fragments
      u32 rv[4];
#pragma unroll
      for (int kt2 = 0; kt2 < 2; ++kt2)
#pragma unroll
        for (int idx = 0; idx < 2; ++idx) {
          u32 send = h ? u[4 * kt2 + idx] : u[4 * kt2 + 2 + idx];
          rv[kt2 * 2 + idx] = (u32)__shfl_xor((int)send, 32);
        }
      union { u32 wd[4]; bf16x8 v; } pf[2];
#pragma unroll
      for (int kt2 = 0; kt2 < 2; ++kt2) {
        pf[kt2].wd[0] = h ? rv[kt2 * 2] : u[4 * kt2];
        pf[kt2].wd[1] = h ? rv[kt2 * 2 + 1] : u[4 * kt2 + 1];
        pf[kt2].wd[2] = h ? u[4 * kt2 + 2] : rv[kt2 * 2];
        pf[kt2].wd[3] = h ? u[4 * kt2 + 3] : rv[kt2 * 2 + 1];
      }

      // PV for this wave's c-half: O[i][c] += P[i][j] * V[c][j]
      __builtin_amdgcn_s_setprio(1);
#pragma unroll
      for (int ct = 0; ct < 4; ++ct) {
        int c = chalf * 128 + ct * 32 + lr;
        bf16x8 vf0 = *(const bf16x8*)(vsl + ((long)h * 256 + c) * 8);
        bf16x8 vf1 = *(const bf16x8*)(vsl + ((long)(2 + h) * 256 + c) * 8);
        acc[ct] = mfma32(pf[0].v, vf0, acc[ct]);
        acc[ct] = mfma32(pf[1].v, vf1, acc[ct]);
      }
      __builtin_amdgcn_s_setprio(0);
    }
  }

  // epilogue: total lsum per row, broadcast 1/lsum, scale, store
  lsum += __shfl_xor(lsum, 32);
  if (h == 0) fw[lr] = 1.0f / lsum;
  asm volatile("s_waitcnt lgkmcnt(0)" ::: "memory");
  f32x4 fq0 = *(const f32x4*)&fw[4 * h];
  f32x4 fq1 = *(const f32x4*)&fw[8 + 4 * h];
  f32x4 fq2 = *(const f32x4*)&fw[16 + 4 * h];
  f32x4 fq3 = *(const f32x4*)&fw[24 + 4 * h];
  f32x16 rlv;
#pragma unroll
  for (int e = 0; e < 4; ++e) {
    rlv[e] = fq0[e]; rlv[4 + e] = fq1[e]; rlv[8 + e] = fq2[e]; rlv[12 + e] = fq3[e];
  }
  u16* ob = ot + ((b * 4096 + i0 + rg * 32) << 8) + chalf * 128;
#pragma unroll
  for (int ct = 0; ct < 4; ++ct) {
    int cl = ct * 32 + lr;
#pragma unroll
    for (int q = 0; q < 4; ++q)
#pragma unroll
      for (int e = 0; e < 4; ++e) {
        int i = 8 * q + 4 * h + e;
        ob[(long)i * 256 + cl] = f2bf(acc[ct][4 * q + e] * rlv[4 * q + e]);
      }
  }
}

// ---------------- launcher ----------------
extern "C" void kernel_launch(void* const* d_in, const int* in_sizes, int n_in,
                              void* d_out, int out_size, void* d_ws, size_t ws_size,
                              hipStream_t stream) {
  const float* x     = (const float*)d_in[0];
  const float* gamma = (const float*)d_in[1];
  const float* beta  = (const float*)d_in[2];
  const float* wq = (const float*)d_in[3];
  const float* bq = (const float*)d_in[4];
  const float* wk = (const float*)d_in[5];
  const float* bk = (const float*)d_in[6];
  const float* wv = (const float*)d_in[7];
  const float* bv = (const float*)d_in[8];
  const float* wp = (const float*)d_in[9];
  const float* bp = (const float*)d_in[10];

  char* ws = (char*)d_ws;
  const long SZ = 16777216;            // one [B][N][C] bf16 tensor
  u16* ht  = (u16*)(ws);
  u16* qtb = (u16*)(ws + SZ);
  u16* ktb = (u16*)(ws + 2 * SZ);      // granule-planar K
  u16* vcb = (u16*)(ws + 3 * SZ);      // granule-planar V
  u16* wbf = (u16*)(ws + 4 * SZ);      // wq|wk|wv|wp, 65536 u16 each
  u16* otb = ht;                       // h dead after QKV; reuse for attn output

  convert_w<<<1024, 256, 0, stream>>>(wq, wk, wv, wp, wbf);
  gn_kernel<<<128, 256, 0, stream>>>(x, gamma, beta, ht);

  dim3 gq(512, 4, 1);   // M=B*N=32768 rows, Nn=256
  gemm_qkv<<<gq, 256, 0, stream>>>(ht, wbf, qtb, ktb, vcb, bq, bk, bv);

  attn_flash<<<512, 256, 0, stream>>>(qtb, ktb, vcb, otb);

  dim3 gp(4, 64, 8);
  gemm_proj<<<gp, 256, 0, stream>>>(wbf + 3 * 65536, otb, (float*)d_out, bp, x);
}